// Round 12
// baseline (121.309 us; speedup 1.0000x reference)
//
#include <hip/hip_runtime.h>
#include <hip/hip_bf16.h>

typedef float f4 __attribute__((ext_vector_type(4)));
typedef float f32x4 __attribute__((ext_vector_type(4)));
typedef short bf16x8 __attribute__((ext_vector_type(8)));

#define D 128
#define SLOTS 64   // fixed bucket/node; Poisson(6): P(deg>64) ~ 1e-44

// float -> bf16 round-to-nearest-even (finite inputs)
__device__ __forceinline__ unsigned f2bf_u(float f) {
    unsigned u = __builtin_bit_cast(unsigned, f);
    unsigned r = 0x7FFFu + ((u >> 16) & 1u);
    return (u + r) >> 16;
}
__device__ __forceinline__ unsigned short f2bf(float f) {
    return (unsigned short)f2bf_u(f);
}
__device__ __forceinline__ float bf2f(short s) {
    unsigned u = ((unsigned)(unsigned short)s) << 16;
    return __builtin_bit_cast(float, u);
}

// ---------------------------------------------------------------------------
// Init: W f32 -> bf16 (vectorized) AND deg[0..N) = 0.
// ---------------------------------------------------------------------------
__global__ __launch_bounds__(256) void init_kernel(
    const float* __restrict__ W, unsigned short* __restrict__ Wbf,
    int* __restrict__ deg, int N)
{
    int i = blockIdx.x * 256 + threadIdx.x;
    if (i < D * D / 4) {
        f4 w = reinterpret_cast<const f4*>(W)[i];
        uint2 o;
        o.x = f2bf_u(w[0]) | (f2bf_u(w[1]) << 16);
        o.y = f2bf_u(w[2]) | (f2bf_u(w[3]) << 16);
        *reinterpret_cast<uint2*>(Wbf + i * 4) = o;
    }
    if (i < N) deg[i] = 0;
}

// ---------------------------------------------------------------------------
// GEMM v6 == v5 structure (col-split, no LDS, 56 VGPR) but launched at
// 2048 blocks (8 blocks/CU -> 32 waves/CU) with __launch_bounds__(256,8).
// DIAGNOSTIC ROUND: only occupancy changed vs R11. If dur doesn't drop,
// the latency-hiding/occupancy hypothesis is refuted.
// Column-split: wave w of the block owns output ct-blocks {2w, 2w+1}:
// W-residency wfrag[2][4] = 32 VGPR. The block's 4 waves cover all 128
// output cols of each 16-row x tile (x loads L1-shared).
// Fragment maps (m89, swapped operands: D = mfma(A=W, B=x)):
//   A: lane holds W[16ct + (lane&15)][kf*32 + (lane>>4)*8 + e]
//   B: lane holds x[tile*16 + (lane&15)][kf*32 + (lane>>4)*8 + e]
//   D: col = lane&15 -> x-row; row = (lane>>4)*4 + r -> outcol
// => lane owns 4 consecutive output cols of one row -> packed dwordx2 store.
// ---------------------------------------------------------------------------
__global__ __launch_bounds__(256, 8) void gemm_mfma(
    const float* __restrict__ x, const unsigned short* __restrict__ Wbf,
    const float* __restrict__ b, unsigned short* __restrict__ ybf, int N)
{
    const int lane = threadIdx.x & 63;
    const int r16  = lane & 15;
    const int g4   = lane >> 4;              // 0..3
    const int ct0  = (threadIdx.x >> 6) * 2; // wave's first ct block (0,2,4,6)

    // W fragments for this wave's two ct blocks (8 x b128 global loads, L2-hot)
    bf16x8 wfrag[2][4];
#pragma unroll
    for (int c = 0; c < 2; ++c)
#pragma unroll
        for (int kf = 0; kf < 4; ++kf)
            wfrag[c][kf] = *reinterpret_cast<const bf16x8*>(
                Wbf + (size_t)(16 * (ct0 + c) + r16) * D + kf * 32 + g4 * 8);

    f4 bias[2];
#pragma unroll
    for (int c = 0; c < 2; ++c)
        bias[c] = *reinterpret_cast<const f4*>(b + 16 * (ct0 + c) + g4 * 4);

    const int ntiles = (N + 15) >> 4;
    for (int tile = blockIdx.x; tile < ntiles; tile += gridDim.x) {
        const int arow = tile * 16 + r16;
        const int srow = (arow < N) ? arow : N - 1;
        const float* xr = x + (size_t)srow * D + g4 * 8;

        union { bf16x8 v; unsigned short s[8]; } afrag[4];
#pragma unroll
        for (int kf = 0; kf < 4; ++kf) {
            f4 x0 = *reinterpret_cast<const f4*>(xr + kf * 32);
            f4 x1 = *reinterpret_cast<const f4*>(xr + kf * 32 + 4);
#pragma unroll
            for (int e = 0; e < 4; ++e) {
                afrag[kf].s[e]     = f2bf(x0[e]);
                afrag[kf].s[e + 4] = f2bf(x1[e]);
            }
        }

        f32x4 acc0 = {0.f, 0.f, 0.f, 0.f};
        f32x4 acc1 = {0.f, 0.f, 0.f, 0.f};
#pragma unroll
        for (int kf = 0; kf < 4; ++kf) {
            acc0 = __builtin_amdgcn_mfma_f32_16x16x32_bf16(
                wfrag[0][kf], afrag[kf].v, acc0, 0, 0, 0);
            acc1 = __builtin_amdgcn_mfma_f32_16x16x32_bf16(
                wfrag[1][kf], afrag[kf].v, acc1, 0, 0, 0);
        }

        if (arow < N) {
            unsigned short* yrow = ybf + (size_t)arow * D + g4 * 4;
            uint2 o0, o1;
            o0.x = f2bf_u(fmaxf(acc0[0] + bias[0][0], 0.f))
                 | (f2bf_u(fmaxf(acc0[1] + bias[0][1], 0.f)) << 16);
            o0.y = f2bf_u(fmaxf(acc0[2] + bias[0][2], 0.f))
                 | (f2bf_u(fmaxf(acc0[3] + bias[0][3], 0.f)) << 16);
            o1.x = f2bf_u(fmaxf(acc1[0] + bias[1][0], 0.f))
                 | (f2bf_u(fmaxf(acc1[1] + bias[1][1], 0.f)) << 16);
            o1.y = f2bf_u(fmaxf(acc1[2] + bias[1][2], 0.f))
                 | (f2bf_u(fmaxf(acc1[3] + bias[1][3], 0.f)) << 16);
            *reinterpret_cast<uint2*>(yrow + 16 * ct0)        = o0;
            *reinterpret_cast<uint2*>(yrow + 16 * (ct0 + 1))  = o1;
        }
    }
}

// ---------------------------------------------------------------------------
// Fused histogram + bucket scatter: p = atomicAdd(deg[s]); slot[s*64+p] = tgt.
// ---------------------------------------------------------------------------
__global__ __launch_bounds__(256) void scatter_hist_kernel(
    const int* __restrict__ src, const int* __restrict__ tgt,
    int* __restrict__ deg, int* __restrict__ slot, int E)
{
    int e = blockIdx.x * 256 + threadIdx.x;
    if (e < E) {
        int s = src[e];
        int p = atomicAdd(&deg[s], 1);
        slot[(size_t)s * SLOTS + p] = tgt[e];
    }
}

// ---------------------------------------------------------------------------
// Aggregate: one node per 16-LANE GROUP (16 nodes / 256-thread block).
// Lane c owns columns c*8..c*8+7 (bf16x8 = 16B). Edge loop unrolled 4-wide
// into 4 independent acc chains; edge indices from one int4 broadcast load.
// Gathers predicated on j+u < d (never dereference garbage slot entries).
// ---------------------------------------------------------------------------
__global__ __launch_bounds__(256) void aggregate_bf16(
    const int* __restrict__ deg, const int* __restrict__ slot,
    const unsigned short* __restrict__ ybf, float* __restrict__ out, int N)
{
    const int g  = threadIdx.x >> 4;      // group 0..15
    const int c8 = (threadIdx.x & 15) * 8;

    const int n = blockIdx.x * 16 + g;
    if (n >= N) return;
    const int d = deg[n];
    const int* sl = slot + (size_t)n * SLOTS;

    float a0[8] = {0,0,0,0,0,0,0,0}, a1[8] = {0,0,0,0,0,0,0,0};
    float a2[8] = {0,0,0,0,0,0,0,0}, a3[8] = {0,0,0,0,0,0,0,0};

    for (int j = 0; j < d; j += 4) {
        int4 tq = *reinterpret_cast<const int4*>(sl + j);   // 16B-aligned bucket
        if (j + 0 < d) {
            bf16x8 v = *reinterpret_cast<const bf16x8*>(ybf + (size_t)tq.x * D + c8);
#pragma unroll
            for (int e = 0; e < 8; ++e) a0[e] += bf2f(v[e]);
        }
        if (j + 1 < d) {
            bf16x8 v = *reinterpret_cast<const bf16x8*>(ybf + (size_t)tq.y * D + c8);
#pragma unroll
            for (int e = 0; e < 8; ++e) a1[e] += bf2f(v[e]);
        }
        if (j + 2 < d) {
            bf16x8 v = *reinterpret_cast<const bf16x8*>(ybf + (size_t)tq.z * D + c8);
#pragma unroll
            for (int e = 0; e < 8; ++e) a2[e] += bf2f(v[e]);
        }
        if (j + 3 < d) {
            bf16x8 v = *reinterpret_cast<const bf16x8*>(ybf + (size_t)tq.w * D + c8);
#pragma unroll
            for (int e = 0; e < 8; ++e) a3[e] += bf2f(v[e]);
        }
    }

    const float dinv = 1.0f / fmaxf((float)d, 1.f);
    f4 o0, o1;
#pragma unroll
    for (int e = 0; e < 4; ++e)
        o0[e] = ((a0[e] + a1[e]) + (a2[e] + a3[e])) * dinv;
#pragma unroll
    for (int e = 4; e < 8; ++e)
        o1[e - 4] = ((a0[e] + a1[e]) + (a2[e] + a3[e])) * dinv;

    float* orow = out + (size_t)n * D + c8;
    *reinterpret_cast<f4*>(orow)     = o0;
    *reinterpret_cast<f4*>(orow + 4) = o1;
}

extern "C" void kernel_launch(void* const* d_in, const int* in_sizes, int n_in,
                              void* d_out, int out_size, void* d_ws, size_t ws_size,
                              hipStream_t stream) {
    const float* x  = (const float*)d_in[0];
    const int*   ei = (const int*)d_in[1];     // [2, E] row-major int32
    const float* W  = (const float*)d_in[2];
    const float* b  = (const float*)d_in[3];
    float* out = (float*)d_out;

    const int N = in_sizes[0] / D;             // 100000
    const int E = in_sizes[1] / 2;             // 600000
    const int* src = ei;
    const int* tgt = ei + E;

    // Workspace: ybf (25.6MB) | Wbf (32KB) | deg (400KB) | slot (25.6MB)
    char* ws = (char*)d_ws;
    unsigned short* ybf = (unsigned short*)ws;   ws += (size_t)N * D * sizeof(unsigned short);
    unsigned short* Wbf = (unsigned short*)ws;   ws += (size_t)D * D * sizeof(unsigned short);
    int* deg  = (int*)ws;                        ws += (size_t)N * sizeof(int);
    int* slot = (int*)ws;                        ws += (size_t)N * SLOTS * sizeof(int);

    // 0) W -> bf16 + deg = 0
    int ib = (N + 255) / 256;                                 // 391 (covers D*D/4)
    init_kernel<<<ib, 256, 0, stream>>>(W, Wbf, deg, N);

    // 1) GEMM + bias + ReLU -> ybf  (2048 blocks = 8 blocks/CU, 32 waves/CU)
    gemm_mfma<<<2048, 256, 0, stream>>>(x, Wbf, b, ybf, N);

    // 2) fused histogram + bucket scatter
    int eb = (E + 255) / 256;                                 // 2344
    scatter_hist_kernel<<<eb, 256, 0, stream>>>(src, tgt, deg, slot, E);

    // 3) gather-aggregate + normalize (1 node per 16-lane group)
    int ab = (N + 15) / 16;                                   // 6250
    aggregate_bf16<<<ab, 256, 0, stream>>>(deg, slot, ybf, out, N);
}

// Round 13
// 118.068 us; speedup vs baseline: 1.0274x; 1.0274x over previous
//
#include <hip/hip_runtime.h>
#include <hip/hip_bf16.h>

typedef float f4 __attribute__((ext_vector_type(4)));
typedef float f32x4 __attribute__((ext_vector_type(4)));
typedef short bf16x8 __attribute__((ext_vector_type(8)));

#define D 128
#define SLOTS 64   // fixed bucket/node; Poisson(6): P(deg>64) ~ 1e-44

// float -> bf16 round-to-nearest-even (finite inputs)
__device__ __forceinline__ unsigned f2bf_u(float f) {
    unsigned u = __builtin_bit_cast(unsigned, f);
    unsigned r = 0x7FFFu + ((u >> 16) & 1u);
    return (u + r) >> 16;
}
__device__ __forceinline__ float bf2f(short s) {
    unsigned u = ((unsigned)(unsigned short)s) << 16;
    return __builtin_bit_cast(float, u);
}
__device__ __forceinline__ uint2 pack8(f4 a, f4 c) {
    uint2 o;
    o.x = f2bf_u(a[0]) | (f2bf_u(a[1]) << 16);
    o.y = f2bf_u(a[2]) | (f2bf_u(a[3]) << 16);
    uint2 p;
    p.x = f2bf_u(c[0]) | (f2bf_u(c[1]) << 16);
    p.y = f2bf_u(c[2]) | (f2bf_u(c[3]) << 16);
    uint2 r; r.x = o.x; r.y = o.y;
    // caller packs two uint2 into uint4; helper returns first half only when
    // used separately. (kept simple below — see init_kernel)
    return r;
}

// ---------------------------------------------------------------------------
// Init: x f32 -> bf16 (STREAMING — moves the conversion OFF the gemm's
// critical path), W f32 -> bf16, deg = 0. Grid sized so one pass covers
// N*D/8 chunks (each thread: 32B read -> 16B write).
// ---------------------------------------------------------------------------
__global__ __launch_bounds__(256) void init_kernel(
    const float* __restrict__ x, const float* __restrict__ W,
    unsigned short* __restrict__ xbf, unsigned short* __restrict__ Wbf,
    int* __restrict__ deg, int N)
{
    const int i = blockIdx.x * 256 + threadIdx.x;

    // x -> bf16 (N*D/8 = 1.6M chunks; grid covers exactly in one pass)
    const int nchunk = N * D / 8;
    if (i < nchunk) {
        f4 a = reinterpret_cast<const f4*>(x)[i * 2];
        f4 c = reinterpret_cast<const f4*>(x)[i * 2 + 1];
        uint4 o;
        o.x = f2bf_u(a[0]) | (f2bf_u(a[1]) << 16);
        o.y = f2bf_u(a[2]) | (f2bf_u(a[3]) << 16);
        o.z = f2bf_u(c[0]) | (f2bf_u(c[1]) << 16);
        o.w = f2bf_u(c[2]) | (f2bf_u(c[3]) << 16);
        reinterpret_cast<uint4*>(xbf)[i] = o;
    }

    // W -> bf16 (first D*D/8 = 2048 threads)
    if (i < D * D / 8) {
        f4 a = reinterpret_cast<const f4*>(W)[i * 2];
        f4 c = reinterpret_cast<const f4*>(W)[i * 2 + 1];
        uint4 o;
        o.x = f2bf_u(a[0]) | (f2bf_u(a[1]) << 16);
        o.y = f2bf_u(a[2]) | (f2bf_u(a[3]) << 16);
        o.z = f2bf_u(c[0]) | (f2bf_u(c[1]) << 16);
        o.w = f2bf_u(c[2]) | (f2bf_u(c[3]) << 16);
        reinterpret_cast<uint4*>(Wbf)[i] = o;
    }

    if (i < N) deg[i] = 0;
}

// ---------------------------------------------------------------------------
// GEMM + scatter v7: bf16 x input — inner body is 4 dwordx4 loads + 8 MFMA +
// 2 dwordx2 stores, ZERO conversions. Col-split: wave w owns ct {2w, 2w+1}
// (wfrag[2][4] = 32 VGPR). Blocks grid-stride (~6 tiles/block @ grid 1024);
// fused histogram+bucket scatter tail (R11: fusion saved ~17us of gaps).
// Fragment maps (m89, swapped operands: D = mfma(A=W, B=x)):
//   A: lane holds W[16ct + (lane&15)][kf*32 + (lane>>4)*8 + e]
//   B: lane holds x[tile*16 + (lane&15)][kf*32 + (lane>>4)*8 + e]
//   D: col = lane&15 -> x-row; row = (lane>>4)*4 + r -> outcol
// => lane owns 4 consecutive output cols of one row -> packed dwordx2 store.
// ---------------------------------------------------------------------------
__global__ __launch_bounds__(256, 8) void gemm_scatter(
    const unsigned short* __restrict__ xbf, const unsigned short* __restrict__ Wbf,
    const float* __restrict__ b, unsigned short* __restrict__ ybf,
    const int* __restrict__ src, const int* __restrict__ tgt,
    int* __restrict__ deg, int* __restrict__ slot, int N, int E)
{
    const int lane = threadIdx.x & 63;
    const int r16  = lane & 15;
    const int g4   = lane >> 4;              // 0..3
    const int ct0  = (threadIdx.x >> 6) * 2; // wave's first ct block (0,2,4,6)

    // W fragments for this wave's two ct blocks (8 x b128 global loads, L2-hot)
    bf16x8 wfrag[2][4];
#pragma unroll
    for (int c = 0; c < 2; ++c)
#pragma unroll
        for (int kf = 0; kf < 4; ++kf)
            wfrag[c][kf] = *reinterpret_cast<const bf16x8*>(
                Wbf + (size_t)(16 * (ct0 + c) + r16) * D + kf * 32 + g4 * 8);

    f4 bias[2];
#pragma unroll
    for (int c = 0; c < 2; ++c)
        bias[c] = *reinterpret_cast<const f4*>(b + 16 * (ct0 + c) + g4 * 4);

    const int ntiles = (N + 15) >> 4;
    for (int tile = blockIdx.x; tile < ntiles; tile += gridDim.x) {
        const int arow = tile * 16 + r16;
        const int srow = (arow < N) ? arow : N - 1;
        const unsigned short* xr = xbf + (size_t)srow * D + g4 * 8;

        bf16x8 afrag[4];
#pragma unroll
        for (int kf = 0; kf < 4; ++kf)
            afrag[kf] = *reinterpret_cast<const bf16x8*>(xr + kf * 32);

        f32x4 acc0 = {0.f, 0.f, 0.f, 0.f};
        f32x4 acc1 = {0.f, 0.f, 0.f, 0.f};
#pragma unroll
        for (int kf = 0; kf < 4; ++kf) {
            acc0 = __builtin_amdgcn_mfma_f32_16x16x32_bf16(
                wfrag[0][kf], afrag[kf], acc0, 0, 0, 0);
            acc1 = __builtin_amdgcn_mfma_f32_16x16x32_bf16(
                wfrag[1][kf], afrag[kf], acc1, 0, 0, 0);
        }

        if (arow < N) {
            unsigned short* yrow = ybf + (size_t)arow * D + g4 * 4;
            uint2 o0, o1;
            o0.x = f2bf_u(fmaxf(acc0[0] + bias[0][0], 0.f))
                 | (f2bf_u(fmaxf(acc0[1] + bias[0][1], 0.f)) << 16);
            o0.y = f2bf_u(fmaxf(acc0[2] + bias[0][2], 0.f))
                 | (f2bf_u(fmaxf(acc0[3] + bias[0][3], 0.f)) << 16);
            o1.x = f2bf_u(fmaxf(acc1[0] + bias[1][0], 0.f))
                 | (f2bf_u(fmaxf(acc1[1] + bias[1][1], 0.f)) << 16);
            o1.y = f2bf_u(fmaxf(acc1[2] + bias[1][2], 0.f))
                 | (f2bf_u(fmaxf(acc1[3] + bias[1][3], 0.f)) << 16);
            *reinterpret_cast<uint2*>(yrow + 16 * ct0)       = o0;
            *reinterpret_cast<uint2*>(yrow + 16 * (ct0 + 1)) = o1;
        }
    }

    // ---- fused histogram + bucket scatter (independent of gemm output) ----
    for (int e = blockIdx.x * 256 + threadIdx.x; e < E; e += gridDim.x * 256) {
        int s = src[e];
        int p = atomicAdd(&deg[s], 1);
        slot[(size_t)s * SLOTS + p] = tgt[e];
    }
}

// ---------------------------------------------------------------------------
// Aggregate: one node per 16-LANE GROUP (16 nodes / 256-thread block).
// Lane c owns columns c*8..c*8+7 (bf16x8 = 16B). Edge loop unrolled 4-wide
// into 4 independent acc chains; edge indices from one int4 broadcast load.
// Gathers predicated on j+u < d (never dereference garbage slot entries).
// ---------------------------------------------------------------------------
__global__ __launch_bounds__(256) void aggregate_bf16(
    const int* __restrict__ deg, const int* __restrict__ slot,
    const unsigned short* __restrict__ ybf, float* __restrict__ out, int N)
{
    const int g  = threadIdx.x >> 4;      // group 0..15
    const int c8 = (threadIdx.x & 15) * 8;

    const int n = blockIdx.x * 16 + g;
    if (n >= N) return;
    const int d = deg[n];
    const int* sl = slot + (size_t)n * SLOTS;

    float a0[8] = {0,0,0,0,0,0,0,0}, a1[8] = {0,0,0,0,0,0,0,0};
    float a2[8] = {0,0,0,0,0,0,0,0}, a3[8] = {0,0,0,0,0,0,0,0};

    for (int j = 0; j < d; j += 4) {
        int4 tq = *reinterpret_cast<const int4*>(sl + j);   // 16B-aligned bucket
        if (j + 0 < d) {
            bf16x8 v = *reinterpret_cast<const bf16x8*>(ybf + (size_t)tq.x * D + c8);
#pragma unroll
            for (int e = 0; e < 8; ++e) a0[e] += bf2f(v[e]);
        }
        if (j + 1 < d) {
            bf16x8 v = *reinterpret_cast<const bf16x8*>(ybf + (size_t)tq.y * D + c8);
#pragma unroll
            for (int e = 0; e < 8; ++e) a1[e] += bf2f(v[e]);
        }
        if (j + 2 < d) {
            bf16x8 v = *reinterpret_cast<const bf16x8*>(ybf + (size_t)tq.z * D + c8);
#pragma unroll
            for (int e = 0; e < 8; ++e) a2[e] += bf2f(v[e]);
        }
        if (j + 3 < d) {
            bf16x8 v = *reinterpret_cast<const bf16x8*>(ybf + (size_t)tq.w * D + c8);
#pragma unroll
            for (int e = 0; e < 8; ++e) a3[e] += bf2f(v[e]);
        }
    }

    const float dinv = 1.0f / fmaxf((float)d, 1.f);
    f4 o0, o1;
#pragma unroll
    for (int e = 0; e < 4; ++e)
        o0[e] = ((a0[e] + a1[e]) + (a2[e] + a3[e])) * dinv;
#pragma unroll
    for (int e = 4; e < 8; ++e)
        o1[e - 4] = ((a0[e] + a1[e]) + (a2[e] + a3[e])) * dinv;

    float* orow = out + (size_t)n * D + c8;
    *reinterpret_cast<f4*>(orow)     = o0;
    *reinterpret_cast<f4*>(orow + 4) = o1;
}

extern "C" void kernel_launch(void* const* d_in, const int* in_sizes, int n_in,
                              void* d_out, int out_size, void* d_ws, size_t ws_size,
                              hipStream_t stream) {
    const float* x  = (const float*)d_in[0];
    const int*   ei = (const int*)d_in[1];     // [2, E] row-major int32
    const float* W  = (const float*)d_in[2];
    const float* b  = (const float*)d_in[3];
    float* out = (float*)d_out;

    const int N = in_sizes[0] / D;             // 100000
    const int E = in_sizes[1] / 2;             // 600000
    const int* src = ei;
    const int* tgt = ei + E;

    // Workspace: xbf (25.6MB) | ybf (25.6MB) | Wbf (32KB) | deg (400KB) | slot (25.6MB)
    char* ws = (char*)d_ws;
    unsigned short* xbf = (unsigned short*)ws;   ws += (size_t)N * D * sizeof(unsigned short);
    unsigned short* ybf = (unsigned short*)ws;   ws += (size_t)N * D * sizeof(unsigned short);
    unsigned short* Wbf = (unsigned short*)ws;   ws += (size_t)D * D * sizeof(unsigned short);
    int* deg  = (int*)ws;                        ws += (size_t)N * sizeof(int);
    int* slot = (int*)ws;                        ws += (size_t)N * SLOTS * sizeof(int);

    // 0) x -> bf16, W -> bf16, deg = 0 (streaming)
    int ib = (N * D / 8 + 255) / 256;                         // 6250
    init_kernel<<<ib, 256, 0, stream>>>(x, W, xbf, Wbf, deg, N);

    // 1) GEMM (bf16 in/out) + bias + ReLU -> ybf, then fused edge scatter
    gemm_scatter<<<1024, 256, 0, stream>>>(xbf, Wbf, b, ybf, src, tgt,
                                           deg, slot, N, E);

    // 2) gather-aggregate + normalize (1 node per 16-lane group)
    int ab = (N + 15) / 16;                                   // 6250
    aggregate_bf16<<<ab, 256, 0, stream>>>(deg, slot, ybf, out, N);
}

// Round 14
// 88.825 us; speedup vs baseline: 1.3657x; 1.3292x over previous
//
#include <hip/hip_runtime.h>
#include <hip/hip_bf16.h>

typedef float f4 __attribute__((ext_vector_type(4)));
typedef float f32x4 __attribute__((ext_vector_type(4)));
typedef short bf16x8 __attribute__((ext_vector_type(8)));

#define D 128
#define SLOTS 64   // fixed bucket/node; Poisson(6): P(deg>64) ~ 1e-44
#define BATCH 3    // tiles per wave-iteration (afrag 48 + wfrag 32 + acc 24 + bias 8 ~ 124 VGPR)

// float -> bf16 round-to-nearest-even (finite inputs)
__device__ __forceinline__ unsigned f2bf_u(float f) {
    unsigned u = __builtin_bit_cast(unsigned, f);
    unsigned r = 0x7FFFu + ((u >> 16) & 1u);
    return (u + r) >> 16;
}
__device__ __forceinline__ float bf2f(short s) {
    unsigned u = ((unsigned)(unsigned short)s) << 16;
    return __builtin_bit_cast(float, u);
}

// ---------------------------------------------------------------------------
// Init: x f32 -> bf16 (streaming), W f32 -> bf16, deg = 0.
// ---------------------------------------------------------------------------
__global__ __launch_bounds__(256) void init_kernel(
    const float* __restrict__ x, const float* __restrict__ W,
    unsigned short* __restrict__ xbf, unsigned short* __restrict__ Wbf,
    int* __restrict__ deg, int N)
{
    const int i = blockIdx.x * 256 + threadIdx.x;

    const int nchunk = N * D / 8;          // 1.6M (grid covers in one pass)
    if (i < nchunk) {
        f4 a = reinterpret_cast<const f4*>(x)[i * 2];
        f4 c = reinterpret_cast<const f4*>(x)[i * 2 + 1];
        uint4 o;
        o.x = f2bf_u(a[0]) | (f2bf_u(a[1]) << 16);
        o.y = f2bf_u(a[2]) | (f2bf_u(a[3]) << 16);
        o.z = f2bf_u(c[0]) | (f2bf_u(c[1]) << 16);
        o.w = f2bf_u(c[2]) | (f2bf_u(c[3]) << 16);
        reinterpret_cast<uint4*>(xbf)[i] = o;
    }

    if (i < D * D / 8) {
        f4 a = reinterpret_cast<const f4*>(W)[i * 2];
        f4 c = reinterpret_cast<const f4*>(W)[i * 2 + 1];
        uint4 o;
        o.x = f2bf_u(a[0]) | (f2bf_u(a[1]) << 16);
        o.y = f2bf_u(a[2]) | (f2bf_u(a[3]) << 16);
        o.z = f2bf_u(c[0]) | (f2bf_u(c[1]) << 16);
        o.w = f2bf_u(c[2]) | (f2bf_u(c[3]) << 16);
        reinterpret_cast<uint4*>(Wbf)[i] = o;
    }

    if (i < N) deg[i] = 0;
}

// ---------------------------------------------------------------------------
// GEMM + scatter v8: TILE-BATCHED. Each wave handles BATCH=3 tiles in ONE
// iteration: 12 independent b128 x-loads issued together (3x the MLP of the
// per-tile loop), then 3 x (8 MFMA + 2 packed stores). Col-split: wave w
// owns ct {2w, 2w+1} (wfrag[2][4] = 32 VGPR); block's 4 waves share x tiles
// via L1. Grid = ceil(ntiles/BATCH) = 2084 (~8 blocks/CU). bounds(256,4)
// keeps VGPR <= 128: NO spill (R12/R13's bounds(256,8) -> 32 VGPR spilled
// wfrag to scratch = +15-20us). Fused scatter tail (R11: saves ~17us).
// Fragment maps (m89, swapped operands: D = mfma(A=W, B=x)):
//   A: lane holds W[16ct + (lane&15)][kf*32 + (lane>>4)*8 + e]
//   B: lane holds x[tile*16 + (lane&15)][kf*32 + (lane>>4)*8 + e]
//   D: col = lane&15 -> x-row; row = (lane>>4)*4 + r -> outcol
// => lane owns 4 consecutive output cols of one row -> packed dwordx2 store.
// ---------------------------------------------------------------------------
__global__ __launch_bounds__(256, 4) void gemm_scatter(
    const unsigned short* __restrict__ xbf, const unsigned short* __restrict__ Wbf,
    const float* __restrict__ b, unsigned short* __restrict__ ybf,
    const int* __restrict__ src, const int* __restrict__ tgt,
    int* __restrict__ deg, int* __restrict__ slot, int N, int E)
{
    const int lane = threadIdx.x & 63;
    const int r16  = lane & 15;
    const int g4   = lane >> 4;              // 0..3
    const int ct0  = (threadIdx.x >> 6) * 2; // wave's first ct block (0,2,4,6)

    // W fragments for this wave's two ct blocks (8 x b128 global loads, L2-hot)
    bf16x8 wfrag[2][4];
#pragma unroll
    for (int c = 0; c < 2; ++c)
#pragma unroll
        for (int kf = 0; kf < 4; ++kf)
            wfrag[c][kf] = *reinterpret_cast<const bf16x8*>(
                Wbf + (size_t)(16 * (ct0 + c) + r16) * D + kf * 32 + g4 * 8);

    f4 bias[2];
#pragma unroll
    for (int c = 0; c < 2; ++c)
        bias[c] = *reinterpret_cast<const f4*>(b + 16 * (ct0 + c) + g4 * 4);

    const int ntiles = (N + 15) >> 4;
    const int t0 = blockIdx.x * BATCH;

    // ---- issue ALL batch loads up front (12 independent b128 loads) ----
    bf16x8 afrag[BATCH][4];
    int rows[BATCH];
#pragma unroll
    for (int tb = 0; tb < BATCH; ++tb) {
        const int tile = t0 + tb;
        const int arow = tile * 16 + r16;
        rows[tb] = (tile < ntiles) ? arow : -1;
        const int srow = (arow < N) ? arow : 0;
        const unsigned short* xr = xbf + (size_t)srow * D + g4 * 8;
        if (tile < ntiles) {
#pragma unroll
            for (int kf = 0; kf < 4; ++kf)
                afrag[tb][kf] = *reinterpret_cast<const bf16x8*>(xr + kf * 32);
        }
    }

    // ---- compute + store per tile ----
#pragma unroll
    for (int tb = 0; tb < BATCH; ++tb) {
        if (rows[tb] < 0) continue;
        f32x4 acc0 = {0.f, 0.f, 0.f, 0.f};
        f32x4 acc1 = {0.f, 0.f, 0.f, 0.f};
#pragma unroll
        for (int kf = 0; kf < 4; ++kf) {
            acc0 = __builtin_amdgcn_mfma_f32_16x16x32_bf16(
                wfrag[0][kf], afrag[tb][kf], acc0, 0, 0, 0);
            acc1 = __builtin_amdgcn_mfma_f32_16x16x32_bf16(
                wfrag[1][kf], afrag[tb][kf], acc1, 0, 0, 0);
        }
        if (rows[tb] < N) {
            unsigned short* yrow = ybf + (size_t)rows[tb] * D + g4 * 4;
            uint2 o0, o1;
            o0.x = f2bf_u(fmaxf(acc0[0] + bias[0][0], 0.f))
                 | (f2bf_u(fmaxf(acc0[1] + bias[0][1], 0.f)) << 16);
            o0.y = f2bf_u(fmaxf(acc0[2] + bias[0][2], 0.f))
                 | (f2bf_u(fmaxf(acc0[3] + bias[0][3], 0.f)) << 16);
            o1.x = f2bf_u(fmaxf(acc1[0] + bias[1][0], 0.f))
                 | (f2bf_u(fmaxf(acc1[1] + bias[1][1], 0.f)) << 16);
            o1.y = f2bf_u(fmaxf(acc1[2] + bias[1][2], 0.f))
                 | (f2bf_u(fmaxf(acc1[3] + bias[1][3], 0.f)) << 16);
            *reinterpret_cast<uint2*>(yrow + 16 * ct0)       = o0;
            *reinterpret_cast<uint2*>(yrow + 16 * (ct0 + 1)) = o1;
        }
    }

    // ---- fused histogram + bucket scatter (independent of gemm output) ----
    for (int e = blockIdx.x * 256 + threadIdx.x; e < E; e += gridDim.x * 256) {
        int s = src[e];
        int p = atomicAdd(&deg[s], 1);
        slot[(size_t)s * SLOTS + p] = tgt[e];
    }
}

// ---------------------------------------------------------------------------
// Aggregate: one node per 16-LANE GROUP (16 nodes / 256-thread block).
// Lane c owns columns c*8..c*8+7 (bf16x8 = 16B). Edge loop unrolled 4-wide
// into 4 independent acc chains; edge indices from one int4 broadcast load.
// Gathers predicated on j+u < d (never dereference garbage slot entries).
// ---------------------------------------------------------------------------
__global__ __launch_bounds__(256) void aggregate_bf16(
    const int* __restrict__ deg, const int* __restrict__ slot,
    const unsigned short* __restrict__ ybf, float* __restrict__ out, int N)
{
    const int g  = threadIdx.x >> 4;      // group 0..15
    const int c8 = (threadIdx.x & 15) * 8;

    const int n = blockIdx.x * 16 + g;
    if (n >= N) return;
    const int d = deg[n];
    const int* sl = slot + (size_t)n * SLOTS;

    float a0[8] = {0,0,0,0,0,0,0,0}, a1[8] = {0,0,0,0,0,0,0,0};
    float a2[8] = {0,0,0,0,0,0,0,0}, a3[8] = {0,0,0,0,0,0,0,0};

    for (int j = 0; j < d; j += 4) {
        int4 tq = *reinterpret_cast<const int4*>(sl + j);   // 16B-aligned bucket
        if (j + 0 < d) {
            bf16x8 v = *reinterpret_cast<const bf16x8*>(ybf + (size_t)tq.x * D + c8);
#pragma unroll
            for (int e = 0; e < 8; ++e) a0[e] += bf2f(v[e]);
        }
        if (j + 1 < d) {
            bf16x8 v = *reinterpret_cast<const bf16x8*>(ybf + (size_t)tq.y * D + c8);
#pragma unroll
            for (int e = 0; e < 8; ++e) a1[e] += bf2f(v[e]);
        }
        if (j + 2 < d) {
            bf16x8 v = *reinterpret_cast<const bf16x8*>(ybf + (size_t)tq.z * D + c8);
#pragma unroll
            for (int e = 0; e < 8; ++e) a2[e] += bf2f(v[e]);
        }
        if (j + 3 < d) {
            bf16x8 v = *reinterpret_cast<const bf16x8*>(ybf + (size_t)tq.w * D + c8);
#pragma unroll
            for (int e = 0; e < 8; ++e) a3[e] += bf2f(v[e]);
        }
    }

    const float dinv = 1.0f / fmaxf((float)d, 1.f);
    f4 o0, o1;
#pragma unroll
    for (int e = 0; e < 4; ++e)
        o0[e] = ((a0[e] + a1[e]) + (a2[e] + a3[e])) * dinv;
#pragma unroll
    for (int e = 4; e < 8; ++e)
        o1[e - 4] = ((a0[e] + a1[e]) + (a2[e] + a3[e])) * dinv;

    float* orow = out + (size_t)n * D + c8;
    *reinterpret_cast<f4*>(orow)     = o0;
    *reinterpret_cast<f4*>(orow + 4) = o1;
}

extern "C" void kernel_launch(void* const* d_in, const int* in_sizes, int n_in,
                              void* d_out, int out_size, void* d_ws, size_t ws_size,
                              hipStream_t stream) {
    const float* x  = (const float*)d_in[0];
    const int*   ei = (const int*)d_in[1];     // [2, E] row-major int32
    const float* W  = (const float*)d_in[2];
    const float* b  = (const float*)d_in[3];
    float* out = (float*)d_out;

    const int N = in_sizes[0] / D;             // 100000
    const int E = in_sizes[1] / 2;             // 600000
    const int* src = ei;
    const int* tgt = ei + E;

    // Workspace: xbf (25.6MB) | ybf (25.6MB) | Wbf (32KB) | deg (400KB) | slot (25.6MB)
    char* ws = (char*)d_ws;
    unsigned short* xbf = (unsigned short*)ws;   ws += (size_t)N * D * sizeof(unsigned short);
    unsigned short* ybf = (unsigned short*)ws;   ws += (size_t)N * D * sizeof(unsigned short);
    unsigned short* Wbf = (unsigned short*)ws;   ws += (size_t)D * D * sizeof(unsigned short);
    int* deg  = (int*)ws;                        ws += (size_t)N * sizeof(int);
    int* slot = (int*)ws;                        ws += (size_t)N * SLOTS * sizeof(int);

    // 0) x -> bf16, W -> bf16, deg = 0 (streaming)
    int ib = (N * D / 8 + 255) / 256;                         // 6250
    init_kernel<<<ib, 256, 0, stream>>>(x, W, xbf, Wbf, deg, N);

    // 1) GEMM (bf16, 3-tile batch per wave) + fused edge scatter
    int ntiles = (N + 15) / 16;                               // 6250
    int gb = (ntiles + BATCH - 1) / BATCH;                    // 2084
    gemm_scatter<<<gb, 256, 0, stream>>>(xbf, Wbf, b, ybf, src, tgt,
                                         deg, slot, N, E);

    // 2) gather-aggregate + normalize (1 node per 16-lane group)
    int ab = (N + 15) / 16;                                   // 6250
    aggregate_bf16<<<ab, 256, 0, stream>>>(deg, slot, ybf, out, N);
}